// Round 2
// baseline (5694.826 us; speedup 1.0000x reference)
//
#include <hip/hip_runtime.h>
#include <math.h>

#define N_NODES 10000
#define N_EDGES 320000

// ---------------- edge_index dtype detection ----------------
// Reference builds edge_index as int64. If the harness hands us raw int64,
// every odd 32-bit word is 0 (values in [0,10000)). With int32, odd words are
// src[1],src[3],... (random in [0,10000)) — P(256 consecutive zeros) ~ 0.
__global__ void k_detect(const int* __restrict__ ei, int* __restrict__ flag) {
  __shared__ int any_nz;
  if (threadIdx.x == 0) any_nz = 0;
  __syncthreads();
  if (ei[2 * threadIdx.x + 1] != 0) atomicOr(&any_nz, 1);
  __syncthreads();
  if (threadIdx.x == 0) *flag = (any_nz == 0) ? 1 : 0;  // 1 => int64 layout
}

__device__ __forceinline__ int2 load_edge(const int* __restrict__ ei, int e, int is64) {
  if (is64) return make_int2(ei[2 * e], ei[2 * N_EDGES + 2 * e]);
  return make_int2(ei[e], ei[N_EDGES + e]);
}

// ---------------- preprocessing ----------------

__global__ void k_init(float* __restrict__ deg, int* __restrict__ cnt) {
  int i = blockIdx.x * blockDim.x + threadIdx.x;
  if (i < N_NODES) { deg[i] = 0.f; cnt[i] = 0; }
}

__global__ void k_deg(const int* __restrict__ ei, const float* __restrict__ w,
                      const int* __restrict__ flag,
                      float* __restrict__ deg, int* __restrict__ cnt) {
  const int is64 = *flag;
  int e = blockIdx.x * blockDim.x + threadIdx.x;
  if (e < N_EDGES) {
    int2 sd = load_edge(ei, e, is64);
    atomicAdd(&deg[sd.x], w[e]);   // deg = segment_sum(edge_weight, src)
    atomicAdd(&cnt[sd.y], 1);      // CSR row sizes (by dst)
  }
}

// single-block: dis = deg>0 ? rsqrt(deg) : 0 ; exclusive-scan cnt -> row_ptr ; zero cursors
__global__ __launch_bounds__(1024) void k_scan(const float* __restrict__ deg,
                                               float* __restrict__ dis,
                                               const int* __restrict__ cnt,
                                               int* __restrict__ row_ptr,
                                               int* __restrict__ cur) {
  __shared__ int sbuf[1024];
  const int tid = threadIdx.x;
  for (int i = tid; i < N_NODES; i += 1024) {
    float d = deg[i];
    dis[i] = d > 0.f ? 1.f / sqrtf(d) : 0.f;
    cur[i] = 0;
  }
  __syncthreads();
  int run = 0;
  for (int base = 0; base < N_NODES; base += 1024) {
    int v = (base + tid < N_NODES) ? cnt[base + tid] : 0;
    sbuf[tid] = v;
    __syncthreads();
    for (int o = 1; o < 1024; o <<= 1) {            // Hillis-Steele inclusive scan
      int t = (tid >= o) ? sbuf[tid - o] : 0;
      __syncthreads();
      sbuf[tid] += t;
      __syncthreads();
    }
    if (base + tid < N_NODES) row_ptr[base + tid + 1] = run + sbuf[tid];
    int tot = sbuf[1023];
    __syncthreads();
    run += tot;
  }
  if (tid == 0) row_ptr[0] = 0;
}

__global__ void k_fill(const int* __restrict__ ei, const float* __restrict__ w,
                       const int* __restrict__ flag, const float* __restrict__ dis,
                       const int* __restrict__ row_ptr, int* __restrict__ cur,
                       int* __restrict__ col, float* __restrict__ val) {
  const int is64 = *flag;
  int e = blockIdx.x * blockDim.x + threadIdx.x;
  if (e < N_EDGES) {
    int2 sd = load_edge(ei, e, is64);
    int p = row_ptr[sd.y] + atomicAdd(&cur[sd.y], 1);
    col[p] = sd.x;
    val[p] = -dis[sd.x] * w[e] * dis[sd.y];   // wn for L_hat = -D^-1/2 A D^-1/2
  }
}

// ---------------- fused Chebyshev step ----------------
// One wave per node. Prop: lane=channel gathers sum_e wn*t_cur[src][c] (CSR row, serial
// edge loop, 4x unrolled for memory-level parallelism). Then t_next = 2*p - t_prev
// (or p when FIRST). GEMM: row broadcast via LDS, lane=output channel,
// acc += t_next @ Wk (+ x@W0 + b when FIRST); LAST writes silu(acc) to h_out.
// Narrow (CIN==2) path: lanes over edges + shfl_xor reduce, no LDS needed.

template <int CIN, int COUT, bool FIRST, bool LAST>
__global__ __launch_bounds__(256) void k_cheb(
    const int* __restrict__ row_ptr, const int* __restrict__ col, const float* __restrict__ val,
    const float* __restrict__ t_cur,   // layer input when FIRST
    const float* __restrict__ t_prev,  // unused when FIRST
    float* __restrict__ t_next,
    const float* __restrict__ Wk,      // W[k] slice (W[1] when FIRST)
    const float* __restrict__ W0,      // FIRST only
    const float* __restrict__ bias,    // FIRST only
    float* __restrict__ acc,
    float* __restrict__ h_out)         // LAST only
{
  __shared__ float ts[4][(CIN > 4) ? CIN : 1];
  __shared__ float xs[4][(FIRST && CIN > 4) ? CIN : 1];
  const int wid = threadIdx.x >> 6, lane = threadIdx.x & 63;
  const int node = blockIdx.x * 4 + wid;   // 10000 % 4 == 0
  const int start = row_ptr[node], end = row_ptr[node + 1];

  float t0 = 0.f, t1 = 0.f;  // CIN==2 results (all lanes)

  if constexpr (CIN == 2) {
    float s0 = 0.f, s1 = 0.f;
    for (int e = start + lane; e < end; e += 64) {
      int c = col[e]; float wv = val[e];
      float2 v = *reinterpret_cast<const float2*>(t_cur + 2 * c);
      s0 += wv * v.x; s1 += wv * v.y;
    }
#pragma unroll
    for (int o = 32; o; o >>= 1) { s0 += __shfl_xor(s0, o); s1 += __shfl_xor(s1, o); }
    if constexpr (FIRST) { t0 = s0; t1 = s1; }
    else { t0 = 2.f * s0 - t_prev[2 * node]; t1 = 2.f * s1 - t_prev[2 * node + 1]; }
    if (lane < 2) t_next[2 * node + lane] = lane ? t1 : t0;
  } else {
    const int cl = (lane < CIN) ? lane : 0;
    float a0 = 0.f, a1 = 0.f, a2 = 0.f, a3 = 0.f;
    int e = start;
    for (; e + 3 < end; e += 4) {   // 4 independent gathers in flight
      int c0 = col[e], c1 = col[e + 1], c2 = col[e + 2], c3 = col[e + 3];
      float w0 = val[e], w1 = val[e + 1], w2 = val[e + 2], w3 = val[e + 3];
      a0 += w0 * t_cur[c0 * CIN + cl];
      a1 += w1 * t_cur[c1 * CIN + cl];
      a2 += w2 * t_cur[c2 * CIN + cl];
      a3 += w3 * t_cur[c3 * CIN + cl];
    }
    for (; e < end; e++) a0 += val[e] * t_cur[col[e] * CIN + cl];
    float p = (a0 + a1) + (a2 + a3);
    float tn;
    if constexpr (FIRST) tn = p;
    else tn = 2.f * p - t_prev[node * CIN + cl];
    if (lane < CIN) {
      t_next[node * CIN + lane] = tn;
      ts[wid][lane] = tn;
      if constexpr (FIRST) xs[wid][lane] = t_cur[node * CIN + lane];
    }
  }
  __syncthreads();

  if (lane < COUT) {
    float sum;
    if constexpr (FIRST) sum = bias[lane];
    else sum = acc[node * COUT + lane];
    if constexpr (CIN == 2) {
      sum += t0 * Wk[lane] + t1 * Wk[COUT + lane];
      if constexpr (FIRST) {
        float x0 = t_cur[2 * node], x1 = t_cur[2 * node + 1];
        sum += x0 * W0[lane] + x1 * W0[COUT + lane];
      }
    } else {
#pragma unroll
      for (int c = 0; c < CIN; c++) sum += ts[wid][c] * Wk[c * COUT + lane];
      if constexpr (FIRST) {
#pragma unroll
        for (int c = 0; c < CIN; c++) sum += xs[wid][c] * W0[c * COUT + lane];
      }
    }
    if constexpr (LAST) {
      h_out[node * COUT + lane] = sum / (1.f + expf(-sum));  // silu
    } else {
      acc[node * COUT + lane] = sum;
    }
  }
}

// final layer: out = sigmoid(h3 @ W4), W4 is (30,)
__global__ __launch_bounds__(256) void k_out(const float* __restrict__ h3,
                                             const float* __restrict__ W4,
                                             float* __restrict__ out) {
  const int wid = threadIdx.x >> 6, lane = threadIdx.x & 63;
  const int node = blockIdx.x * 4 + wid;
  float v = (lane < 30) ? h3[node * 30 + lane] * W4[lane] : 0.f;
#pragma unroll
  for (int o = 32; o; o >>= 1) v += __shfl_xor(v, o);
  if (lane == 0) out[node] = 1.f / (1.f + expf(-v));
}

// ---------------- host-side layer driver ----------------

template <int CI, int CO>
static void run_layer(const float* h_in, float* h_out, const float* W, const float* b, int K,
                      const int* rowp, const int* col, const float* val,
                      float* tA, float* tB, float* tC, float* accb, hipStream_t stream) {
  const int GB = N_NODES / 4;
  k_cheb<CI, CO, true, false><<<GB, 256, 0, stream>>>(rowp, col, val, h_in, nullptr, tA,
                                                      W + CI * CO, W, b, accb, nullptr);
  float* ptrs[3] = {tA, tB, tC};
  for (int k = 2; k < K; k++) {
    const float* prev = (k == 2) ? h_in : ptrs[(k - 3) % 3];
    const float* cur  = ptrs[(k - 2) % 3];
    float* next       = ptrs[(k - 1) % 3];
    if (k < K - 1)
      k_cheb<CI, CO, false, false><<<GB, 256, 0, stream>>>(rowp, col, val, cur, prev, next,
                                                           W + (size_t)k * CI * CO, nullptr,
                                                           nullptr, accb, nullptr);
    else
      k_cheb<CI, CO, false, true><<<GB, 256, 0, stream>>>(rowp, col, val, cur, prev, next,
                                                          W + (size_t)k * CI * CO, nullptr,
                                                          nullptr, accb, h_out);
  }
}

extern "C" void kernel_launch(void* const* d_in, const int* in_sizes, int n_in,
                              void* d_out, int out_size, void* d_ws, size_t ws_size,
                              hipStream_t stream) {
  const float* x  = (const float*)d_in[0];
  const int*   ei = (const int*)d_in[1];   // (2, E), int32 or raw int64 (detected)
  const float* ew = (const float*)d_in[2];
  const float* W1 = (const float*)d_in[3];
  const float* b1 = (const float*)d_in[4];
  const float* W2 = (const float*)d_in[5];
  const float* b2 = (const float*)d_in[6];
  const float* W3 = (const float*)d_in[7];
  const float* b3 = (const float*)d_in[8];
  const float* W4 = (const float*)d_in[9];
  float* out = (float*)d_out;

  // workspace carve-out (~18 MB total)
  char* ws = (char*)d_ws;
  size_t off = 0;
  auto alloc = [&](size_t bytes) {
    void* p = ws + off;
    off += (bytes + 255) & ~size_t(255);
    return p;
  };
  float* deg  = (float*)alloc(N_NODES * 4);
  float* dis  = (float*)alloc(N_NODES * 4);
  int*   cnt  = (int*)alloc(N_NODES * 4);
  int*   cur  = (int*)alloc(N_NODES * 4);
  int*   rowp = (int*)alloc((N_NODES + 1) * 4);
  int*   col  = (int*)alloc(N_EDGES * 4);
  float* val  = (float*)alloc(N_EDGES * 4);
  int*   flag = (int*)alloc(256);
  float* tA   = (float*)alloc(N_NODES * 60 * 4);
  float* tB   = (float*)alloc(N_NODES * 60 * 4);
  float* tC   = (float*)alloc(N_NODES * 60 * 4);
  float* accb = (float*)alloc(N_NODES * 60 * 4);
  float* h1   = (float*)alloc(N_NODES * 60 * 4);
  float* h2   = (float*)alloc(N_NODES * 60 * 4);
  float* h3   = (float*)alloc(N_NODES * 30 * 4);

  // build normalized-Laplacian CSR (by dst) each call (ws is re-poisoned)
  k_detect<<<1, 256, 0, stream>>>(ei, flag);
  k_init<<<(N_NODES + 255) / 256, 256, 0, stream>>>(deg, cnt);
  k_deg<<<(N_EDGES + 255) / 256, 256, 0, stream>>>(ei, ew, flag, deg, cnt);
  k_scan<<<1, 1024, 0, stream>>>(deg, dis, cnt, rowp, cur);
  k_fill<<<(N_EDGES + 255) / 256, 256, 0, stream>>>(ei, ew, flag, dis, rowp, cur, col, val);

  run_layer<2, 60>(x, h1, W1, b1, 200, rowp, col, val, tA, tB, tC, accb, stream);
  run_layer<60, 60>(h1, h2, W2, b2, 200, rowp, col, val, tA, tB, tC, accb, stream);
  run_layer<60, 30>(h2, h3, W3, b3, 20, rowp, col, val, tA, tB, tC, accb, stream);
  k_out<<<N_NODES / 4, 256, 0, stream>>>(h3, W4, out);
}